// Round 3
// baseline (1195.608 us; speedup 1.0000x reference)
//
#include <hip/hip_runtime.h>
#include <math.h>

#define N_NODES 20000
#define N_EDGES 160000
// ws layout (bytes). Total ~46.5 MB.
static const size_t OFF_G   = 0;                                   // g_ws [64][N_EDGES] f32 (k-major)
static const size_t OFF_SH  = OFF_G  + (size_t)64 * N_EDGES * 4;   // sh_ws [8][N_EDGES] f32
static const size_t OFF_W4R = OFF_SH + (size_t)8  * N_EDGES * 4;   // W4R [4096][16] f32 (12 used + 4 pad)
static const size_t OFF_W1T = OFF_W4R + (size_t)4096 * 16 * 4;     // w1T [64][16]
static const size_t OFF_W2T = OFF_W1T + (size_t)64 * 16 * 4;       // w2T [64][64]
static const size_t OFF_W3T = OFF_W2T + (size_t)64 * 64 * 4;       // w3T [64][64]
static const size_t OFF_AI  = OFF_W3T + (size_t)64 * 64 * 4;       // AiTable [10][8]
static const size_t OFF_CNT = OFF_AI + 512;                        // cnt [N_NODES] f32

// prep_kernel index-space bounds
#define PREP_W4R_END 49152                     // 4096*12
#define PREP_W1T_END (PREP_W4R_END + 1024)     // 64*16
#define PREP_W2T_END (PREP_W1T_END + 4096)     // 64*64
#define PREP_W3T_END (PREP_W2T_END + 4096)     // 64*64  -> total 58368

__device__ __forceinline__ float silu_f(float x) {
    return x / (1.0f + __expf(-x));
}

// ---------------- K1: node-type MLP table (10 types, Ai = 8 floats each) -------------
__global__ void ai_table_kernel(const float* __restrict__ emb,
                                const float* __restrict__ w1, const float* __restrict__ b1,
                                const float* __restrict__ w2, const float* __restrict__ b2,
                                const float* __restrict__ w3, const float* __restrict__ b3,
                                float* __restrict__ ai_out) {
    __shared__ float h1[64];
    __shared__ float h2[32];
    int t = blockIdx.x;        // atom type 0..9
    int j = threadIdx.x;       // 0..63
    float acc = b1[j];
    #pragma unroll
    for (int i = 0; i < 16; i++) acc += emb[t * 16 + i] * w1[i * 64 + j];
    h1[j] = silu_f(acc);
    __syncthreads();
    if (j < 32) {
        float a2 = b2[j];
        #pragma unroll
        for (int i = 0; i < 64; i++) a2 += h1[i] * w2[i * 32 + j];
        h2[j] = silu_f(a2);
    }
    __syncthreads();
    if (j < 8) {
        float a3 = b3[j];
        #pragma unroll
        for (int i = 0; i < 32; i++) a3 += h2[i] * w3[i * 8 + j];
        ai_out[t * 8 + j] = a3;   // no activation on final layer
    }
}

// ---------------- K2: weight reorder / transposes ------------------------------------
__global__ void prep_kernel(const float* __restrict__ fc_w1, const float* __restrict__ fc_w2,
                            const float* __restrict__ fc_w3, const float* __restrict__ fc_w4,
                            float* __restrict__ w4r, float* __restrict__ w1t,
                            float* __restrict__ w2t, float* __restrict__ w3t) {
    int idx = blockIdx.x * 256 + threadIdx.x;
    if (idx < PREP_W4R_END) {
        int kappa = idx / 12;
        int j = idx - kappa * 12;
        int l = j >> 2, w = j & 3;
        int v = kappa & 7, u = (kappa >> 3) & 7, k = kappa >> 6;
        w4r[kappa * 16 + j] = fc_w4[k * 768 + ((l * 8 + u) * 8 + v) * 4 + w];
    } else if (idx < PREP_W1T_END) {
        int t = idx - PREP_W4R_END; int j = t >> 4, i = t & 15;
        w1t[j * 16 + i] = fc_w1[i * 64 + j];
    } else if (idx < PREP_W2T_END) {
        int t = idx - PREP_W1T_END; int j = t >> 6, i = t & 63;
        w2t[j * 64 + i] = fc_w2[i * 64 + j];
    } else if (idx < PREP_W3T_END) {
        int t = idx - PREP_W2T_END; int j = t >> 6, i = t & 63;
        w3t[j * 64 + i] = fc_w3[i * 64 + j];
    }
}

// ---------------- K3: per-edge geometry + radial MLP (all-register) ------------------
__global__ __launch_bounds__(256) void edge_g_kernel(
        const float* __restrict__ pos, const int* __restrict__ batch,
        const int* __restrict__ esrc, const int* __restrict__ edst,
        const float* __restrict__ shifts, const float* __restrict__ cell,
        const float* __restrict__ w1t, const float* __restrict__ w2t,
        const float* __restrict__ w3t,
        float* __restrict__ g_ws, float* __restrict__ sh_ws) {
    int e = blockIdx.x * 256 + threadIdx.x;   // grid sized exactly

    int s = esrc[e], d = edst[e];
    int gb = batch[s];
    float t0 = shifts[e * 3 + 0], t1 = shifts[e * 3 + 1], t2 = shifts[e * 3 + 2];
    const float* C = cell + gb * 9;
    float shx = t0 * C[0] + t1 * C[3] + t2 * C[6];
    float shy = t0 * C[1] + t1 * C[4] + t2 * C[7];
    float shz = t0 * C[2] + t1 * C[5] + t2 * C[8];
    float ex = pos[d * 3 + 0] - pos[s * 3 + 0] + shx;
    float ey = pos[d * 3 + 1] - pos[s * 3 + 1] + shy;
    float ez = pos[d * 3 + 2] - pos[s * 3 + 2] + shz;
    float r = sqrtf(ex * ex + ey * ey + ez * ez);
    float inv = 1.0f / fmaxf(r, 1e-9f);
    float x = ex * inv, y = ey * inv, z = ez * inv;

    const float S3  = 1.7320508075688772f;
    const float S15 = 3.8729833462074170f;
    const float S5  = 2.2360679774997896f;
    sh_ws[0 * N_EDGES + e] = S3 * y;
    sh_ws[1 * N_EDGES + e] = S3 * z;
    sh_ws[2 * N_EDGES + e] = S3 * x;
    sh_ws[3 * N_EDGES + e] = S15 * x * y;
    sh_ws[4 * N_EDGES + e] = S15 * y * z;
    sh_ws[5 * N_EDGES + e] = 0.5f * S5 * (3.0f * z * z - 1.0f);
    sh_ws[6 * N_EDGES + e] = S15 * x * z;
    sh_ws[7 * N_EDGES + e] = 0.5f * S15 * (x * x - y * y);

    // radial basis
    float rb[16];
    const float step = 5.0f / 17.0f;
    const float istep = 17.0f / 5.0f;
    const float rsc = 4.0f / 1.12f;
    #pragma unroll
    for (int i = 0; i < 16; i++) {
        float dd = (r - (float)(i + 1) * step) * istep;
        rb[i] = __expf(-dd * dd) * rsc;
    }

    float h[64], hn[64];

    // L1: 16 -> 64 into h
    #pragma unroll 2
    for (int j = 0; j < 64; j++) {
        const float* wr = w1t + j * 16;     // uniform -> scalar loads
        float a0 = 0, a1 = 0, a2 = 0, a3 = 0;
        #pragma unroll
        for (int i = 0; i < 16; i += 4) {
            a0 += rb[i] * wr[i];         a1 += rb[i + 1] * wr[i + 1];
            a2 += rb[i + 2] * wr[i + 2]; a3 += rb[i + 3] * wr[i + 3];
        }
        h[j] = silu_f(((a0 + a1) + (a2 + a3)) * 0.25f);
    }

    // L2: 64 -> 64  h -> hn
    #pragma unroll 2
    for (int j = 0; j < 64; j++) {
        const float* wr = w2t + j * 64;
        float a0 = 0, a1 = 0, a2 = 0, a3 = 0;
        #pragma unroll
        for (int i = 0; i < 64; i += 4) {
            a0 += h[i] * wr[i];           a1 += h[i + 1] * wr[i + 1];
            a2 += h[i + 2] * wr[i + 2];   a3 += h[i + 3] * wr[i + 3];
        }
        hn[j] = silu_f(((a0 + a1) + (a2 + a3)) * 0.125f);
    }

    // L3: 64 -> 64  hn -> g (k-major global)
    #pragma unroll 2
    for (int j = 0; j < 64; j++) {
        const float* wr = w3t + j * 64;
        float a0 = 0, a1 = 0, a2 = 0, a3 = 0;
        #pragma unroll
        for (int i = 0; i < 64; i += 4) {
            a0 += hn[i] * wr[i];          a1 += hn[i + 1] * wr[i + 1];
            a2 += hn[i + 2] * wr[i + 2];  a3 += hn[i + 3] * wr[i + 3];
        }
        g_ws[j * N_EDGES + e] = silu_f(((a0 + a1) + (a2 + a3)) * 0.125f);
    }
}

// ---------------- K4: main contraction, k-split 4-way across waves -------------------
// Block = 256 threads = 4 waves over the SAME 64 edges; wave w owns k in [16w,16w+16).
// Partials reduced via LDS; wave w then owns output column w in the epilogue.
__global__ __launch_bounds__(256) void main_kernel(
        const int* __restrict__ A, const int* __restrict__ esrc, const int* __restrict__ edst,
        const float* __restrict__ g_ws, const float* __restrict__ sh_ws,
        const float* __restrict__ w4r, const float* __restrict__ ai_tab,
        float* __restrict__ out, float* __restrict__ cnt) {
    __shared__ float part[4 * 12 * 64];       // [wave][j][lane] 12 KB
    int tid = threadIdx.x;
    int lane = tid & 63;
    int wv = tid >> 6;                        // 0..3 = k-chunk / output column
    int e = blockIdx.x * 64 + lane;           // grid sized exactly: 2500*64

    int s = esrc[e], d = edst[e];
    int ts = A[s], td = A[d];

    float a[8], b[8];
    {
        const float4* ap = (const float4*)(ai_tab + ts * 8);
        float4 x0 = ap[0], x1 = ap[1];
        a[0] = x0.x; a[1] = x0.y; a[2] = x0.z; a[3] = x0.w;
        a[4] = x1.x; a[5] = x1.y; a[6] = x1.z; a[7] = x1.w;
        const float4* bp = (const float4*)(ai_tab + td * 8);
        float4 y0 = bp[0], y1 = bp[1];
        b[0] = y0.x; b[1] = y0.y; b[2] = y0.z; b[3] = y0.w;
        b[4] = y1.x; b[5] = y1.y; b[6] = y1.z; b[7] = y1.w;
    }

    float sv[12];
    #pragma unroll
    for (int i = 0; i < 12; i++) sv[i] = 0.0f;

    int k0 = wv * 16;
    for (int k = k0; k < k0 + 16; k++) {
        float gk = g_ws[k * N_EDGES + e];       // coalesced per wave
        #pragma unroll
        for (int u = 0; u < 8; u++) {
            float ga = gk * a[u];
            #pragma unroll
            for (int v = 0; v < 8; v++) {
                float f2 = ga * b[v];
                const float* wr = w4r + (((k * 8 + u) * 8 + v) << 4);  // uniform -> scalar
                float4 wa = *(const float4*)(wr);
                float4 wb = *(const float4*)(wr + 4);
                float4 wc = *(const float4*)(wr + 8);
                sv[0] += f2 * wa.x; sv[1] += f2 * wa.y; sv[2]  += f2 * wa.z; sv[3]  += f2 * wa.w;
                sv[4] += f2 * wb.x; sv[5] += f2 * wb.y; sv[6]  += f2 * wb.z; sv[7]  += f2 * wb.w;
                sv[8] += f2 * wc.x; sv[9] += f2 * wc.y; sv[10] += f2 * wc.z; sv[11] += f2 * wc.w;
            }
        }
    }

    #pragma unroll
    for (int j = 0; j < 12; j++) part[wv * 768 + j * 64 + lane] = sv[j];
    __syncthreads();

    // Reduction + epilogue: this thread owns (edge=lane_of_block, output column w=wv).
    float s0 = 0.0f, s1 = 0.0f, s2 = 0.0f;
    #pragma unroll
    for (int p = 0; p < 4; p++) {
        s0 += part[p * 768 + (wv + 0) * 64 + lane];   // j=wv   -> l=0
        s1 += part[p * 768 + (wv + 4) * 64 + lane];   // j=wv+4 -> l=1
        s2 += part[p * 768 + (wv + 8) * 64 + lane];   // j=wv+8 -> l=2
    }
    const float isc = 1.0f / 64.0f;
    s0 *= isc; s1 *= isc; s2 *= isc;

    float shv[8];
    #pragma unroll
    for (int i = 0; i < 8; i++) shv[i] = sh_ws[i * N_EDGES + e];

    float* o = out + d * 36;
    atomicAdd(o + wv, s0);
    #pragma unroll
    for (int jj = 0; jj < 3; jj++) atomicAdd(o + 4 + wv * 3 + jj, s1 * shv[jj]);
    #pragma unroll
    for (int jj = 0; jj < 5; jj++) atomicAdd(o + 16 + wv * 5 + jj, s2 * shv[3 + jj]);
    if (wv == 0) atomicAdd(cnt + d, 1.0f);
}

// ---------------- K5: divide by per-node edge count ----------------------------------
__global__ void finalize_kernel(float* __restrict__ out, const float* __restrict__ cnt) {
    int i = blockIdx.x * 256 + threadIdx.x;
    if (i < N_NODES * 36) {
        float c = cnt[i / 36];
        out[i] = out[i] / fmaxf(c, 1.0f);
    }
}

extern "C" void kernel_launch(void* const* d_in, const int* in_sizes, int n_in,
                              void* d_out, int out_size, void* d_ws, size_t ws_size,
                              hipStream_t stream) {
    const float* pos    = (const float*)d_in[0];
    const int*   A      = (const int*)d_in[1];
    const int*   batch  = (const int*)d_in[2];
    const int*   esrc   = (const int*)d_in[3];
    const int*   edst   = (const int*)d_in[4];
    const float* shifts = (const float*)d_in[5];
    const float* cell   = (const float*)d_in[6];
    const float* emb    = (const float*)d_in[7];
    const float* fw1    = (const float*)d_in[8];
    const float* fb1    = (const float*)d_in[9];
    const float* fw2    = (const float*)d_in[10];
    const float* fb2    = (const float*)d_in[11];
    const float* fw3    = (const float*)d_in[12];
    const float* fb3    = (const float*)d_in[13];
    const float* fcw1   = (const float*)d_in[14];
    const float* fcw2   = (const float*)d_in[15];
    const float* fcw3   = (const float*)d_in[16];
    const float* fcw4   = (const float*)d_in[17];
    float* out = (float*)d_out;

    char* ws = (char*)d_ws;
    float* g_ws   = (float*)(ws + OFF_G);
    float* sh_ws  = (float*)(ws + OFF_SH);
    float* w4r    = (float*)(ws + OFF_W4R);
    float* w1t    = (float*)(ws + OFF_W1T);
    float* w2t    = (float*)(ws + OFF_W2T);
    float* w3t    = (float*)(ws + OFF_W3T);
    float* ai_tab = (float*)(ws + OFF_AI);
    float* cnt    = (float*)(ws + OFF_CNT);

    hipMemsetAsync(out, 0, (size_t)N_NODES * 36 * 4, stream);
    hipMemsetAsync(cnt, 0, (size_t)N_NODES * 4, stream);

    ai_table_kernel<<<10, 64, 0, stream>>>(emb, fw1, fb1, fw2, fb2, fw3, fb3, ai_tab);
    prep_kernel<<<(PREP_W3T_END + 255) / 256, 256, 0, stream>>>(fcw1, fcw2, fcw3, fcw4, w4r, w1t, w2t, w3t);
    edge_g_kernel<<<N_EDGES / 256, 256, 0, stream>>>(
        pos, batch, esrc, edst, shifts, cell, w1t, w2t, w3t, g_ws, sh_ws);
    main_kernel<<<N_EDGES / 64, 256, 0, stream>>>(
        A, esrc, edst, g_ws, sh_ws, w4r, ai_tab, out, cnt);
    finalize_kernel<<<(N_NODES * 36 + 255) / 256, 256, 0, stream>>>(out, cnt);
}

// Round 4
// 587.080 us; speedup vs baseline: 2.0365x; 2.0365x over previous
//
#include <hip/hip_runtime.h>
#include <math.h>

#define N_NODES 20000
#define N_EDGES 160000

// ws layout (bytes). Tiny now (~350 KB).
static const size_t OFF_T   = 0;                                   // T [100][64][12] f32
static const size_t OFF_W1T = OFF_T   + (size_t)100 * 64 * 12 * 4; // w1T [64][16]
static const size_t OFF_W2T = OFF_W1T + (size_t)64 * 16 * 4;       // w2T [64][64]
static const size_t OFF_W3T = OFF_W2T + (size_t)64 * 64 * 4;       // w3T [64][64]
static const size_t OFF_AI  = OFF_W3T + (size_t)64 * 64 * 4;       // AiTable [10][8]
static const size_t OFF_CNT = OFF_AI + 512;                        // cnt [N_NODES] f32

// prep_kernel index-space bounds (transposes only; fc_w4 consumed by build_T directly)
#define PREP_W1T_END 1024                      // 64*16
#define PREP_W2T_END (PREP_W1T_END + 4096)     // 64*64
#define PREP_W3T_END (PREP_W2T_END + 4096)     // 64*64 -> total 9216

__device__ __forceinline__ float silu_f(float x) {
    return x / (1.0f + __expf(-x));
}

// ---------------- K1: node-type MLP table (10 types, Ai = 8 floats each) -------------
__global__ void ai_table_kernel(const float* __restrict__ emb,
                                const float* __restrict__ w1, const float* __restrict__ b1,
                                const float* __restrict__ w2, const float* __restrict__ b2,
                                const float* __restrict__ w3, const float* __restrict__ b3,
                                float* __restrict__ ai_out) {
    __shared__ float h1[64];
    __shared__ float h2[32];
    int t = blockIdx.x;        // atom type 0..9
    int j = threadIdx.x;       // 0..63
    float acc = b1[j];
    #pragma unroll
    for (int i = 0; i < 16; i++) acc += emb[t * 16 + i] * w1[i * 64 + j];
    h1[j] = silu_f(acc);
    __syncthreads();
    if (j < 32) {
        float a2 = b2[j];
        #pragma unroll
        for (int i = 0; i < 64; i++) a2 += h1[i] * w2[i * 32 + j];
        h2[j] = silu_f(a2);
    }
    __syncthreads();
    if (j < 8) {
        float a3 = b3[j];
        #pragma unroll
        for (int i = 0; i < 32; i++) a3 += h2[i] * w3[i * 8 + j];
        ai_out[t * 8 + j] = a3;   // no activation on final layer
    }
}

// ---------------- K2: weight transposes for the radial MLP ---------------------------
__global__ void prep_kernel(const float* __restrict__ fc_w1, const float* __restrict__ fc_w2,
                            const float* __restrict__ fc_w3,
                            float* __restrict__ w1t, float* __restrict__ w2t,
                            float* __restrict__ w3t) {
    int idx = blockIdx.x * 256 + threadIdx.x;
    if (idx < PREP_W1T_END) {
        int j = idx >> 4, i = idx & 15;
        w1t[j * 16 + i] = fc_w1[i * 64 + j];
    } else if (idx < PREP_W2T_END) {
        int t = idx - PREP_W1T_END; int j = t >> 6, i = t & 63;
        w2t[j * 64 + i] = fc_w2[i * 64 + j];
    } else if (idx < PREP_W3T_END) {
        int t = idx - PREP_W2T_END; int j = t >> 6, i = t & 63;
        w3t[j * 64 + i] = fc_w3[i * 64 + j];
    }
}

// ---------------- K2b: T table -------------------------------------------------------
// T[pair=ts*10+td][k][j=(l*4+w)] = sum_{u,v} Ai[ts][u] * Ai[td][v] * fc_w4[k][l*256+u*32+v*4+w]
// One thread per (pair,k): 64 (u,v) iters x (3 float4 loads + 12 FMA). 6400 threads total.
__global__ void build_T_kernel(const float* __restrict__ fc_w4,
                               const float* __restrict__ ai_tab,
                               float* __restrict__ T) {
    int idx = blockIdx.x * 256 + threadIdx.x;
    if (idx >= 6400) return;
    int pair = idx >> 6;          // 0..99
    int k = idx & 63;
    int ts = pair / 10, td = pair - ts * 10;

    float a[8], b[8];
    #pragma unroll
    for (int i = 0; i < 8; i++) a[i] = ai_tab[ts * 8 + i];
    #pragma unroll
    for (int i = 0; i < 8; i++) b[i] = ai_tab[td * 8 + i];

    float sv[12];
    #pragma unroll
    for (int i = 0; i < 12; i++) sv[i] = 0.0f;

    const float* wk = fc_w4 + k * 768;
    #pragma unroll 2
    for (int u = 0; u < 8; u++) {
        #pragma unroll
        for (int v = 0; v < 8; v++) {
            float ab = a[u] * b[v];
            const float* wp = wk + u * 32 + v * 4;
            float4 w0 = *(const float4*)(wp);
            float4 w1 = *(const float4*)(wp + 256);
            float4 w2 = *(const float4*)(wp + 512);
            sv[0] += ab * w0.x; sv[1] += ab * w0.y; sv[2]  += ab * w0.z; sv[3]  += ab * w0.w;
            sv[4] += ab * w1.x; sv[5] += ab * w1.y; sv[6]  += ab * w1.z; sv[7]  += ab * w1.w;
            sv[8] += ab * w2.x; sv[9] += ab * w2.y; sv[10] += ab * w2.z; sv[11] += ab * w2.w;
        }
    }
    float* tp = T + pair * 768 + k * 12;
    #pragma unroll
    for (int j = 0; j < 12; j++) tp[j] = sv[j];
}

// ---------------- K3: fused edge kernel ----------------------------------------------
// geometry -> radial basis -> MLP L1/L2 -> (L3 fused with T matvec) -> sh epilogue -> atomics
__global__ __launch_bounds__(256) void edge_fused_kernel(
        const float* __restrict__ pos, const int* __restrict__ batch,
        const int* __restrict__ esrc, const int* __restrict__ edst,
        const float* __restrict__ shifts, const float* __restrict__ cell,
        const int* __restrict__ A,
        const float* __restrict__ w1t, const float* __restrict__ w2t,
        const float* __restrict__ w3t, const float* __restrict__ T,
        float* __restrict__ out, float* __restrict__ cnt) {
    int e = blockIdx.x * 256 + threadIdx.x;   // grid sized exactly

    int s = esrc[e], d = edst[e];
    int gb = batch[s];
    float t0 = shifts[e * 3 + 0], t1 = shifts[e * 3 + 1], t2 = shifts[e * 3 + 2];
    const float* C = cell + gb * 9;
    float shx = t0 * C[0] + t1 * C[3] + t2 * C[6];
    float shy = t0 * C[1] + t1 * C[4] + t2 * C[7];
    float shz = t0 * C[2] + t1 * C[5] + t2 * C[8];
    float ex = pos[d * 3 + 0] - pos[s * 3 + 0] + shx;
    float ey = pos[d * 3 + 1] - pos[s * 3 + 1] + shy;
    float ez = pos[d * 3 + 2] - pos[s * 3 + 2] + shz;
    float r = sqrtf(ex * ex + ey * ey + ez * ez);
    float inv = 1.0f / fmaxf(r, 1e-9f);
    float x = ex * inv, y = ey * inv, z = ez * inv;

    // radial basis
    float rb[16];
    const float step = 5.0f / 17.0f;
    const float istep = 17.0f / 5.0f;
    const float rsc = 4.0f / 1.12f;
    #pragma unroll
    for (int i = 0; i < 16; i++) {
        float dd = (r - (float)(i + 1) * step) * istep;
        rb[i] = __expf(-dd * dd) * rsc;
    }

    float h[64], hn[64];

    // L1: 16 -> 64 into h (weights via uniform addresses -> scalar loads)
    #pragma unroll 2
    for (int j = 0; j < 64; j++) {
        const float* wr = w1t + j * 16;
        float a0 = 0, a1 = 0, a2 = 0, a3 = 0;
        #pragma unroll
        for (int i = 0; i < 16; i += 4) {
            a0 += rb[i] * wr[i];         a1 += rb[i + 1] * wr[i + 1];
            a2 += rb[i + 2] * wr[i + 2]; a3 += rb[i + 3] * wr[i + 3];
        }
        h[j] = silu_f(((a0 + a1) + (a2 + a3)) * 0.25f);
    }

    // L2: 64 -> 64  h -> hn
    #pragma unroll 2
    for (int j = 0; j < 64; j++) {
        const float* wr = w2t + j * 64;
        float a0 = 0, a1 = 0, a2 = 0, a3 = 0;
        #pragma unroll
        for (int i = 0; i < 64; i += 4) {
            a0 += h[i] * wr[i];           a1 += h[i + 1] * wr[i + 1];
            a2 += h[i + 2] * wr[i + 2];   a3 += h[i + 3] * wr[i + 3];
        }
        hn[j] = silu_f(((a0 + a1) + (a2 + a3)) * 0.125f);
    }

    // L3 fused with T-matvec: g_k = silu(hn . w3_k / 8);  sv[:] += g_k * T[pair][k][:]
    int pair = A[s] * 10 + A[d];
    const float* Tp = T + pair * 768;

    float sv[12];
    #pragma unroll
    for (int i = 0; i < 12; i++) sv[i] = 0.0f;

    #pragma unroll 2
    for (int k = 0; k < 64; k++) {
        const float* wr = w3t + k * 64;   // uniform -> scalar loads
        float a0 = 0, a1 = 0, a2 = 0, a3 = 0;
        #pragma unroll
        for (int i = 0; i < 64; i += 4) {
            a0 += hn[i] * wr[i];          a1 += hn[i + 1] * wr[i + 1];
            a2 += hn[i + 2] * wr[i + 2];  a3 += hn[i + 3] * wr[i + 3];
        }
        float gk = silu_f(((a0 + a1) + (a2 + a3)) * 0.125f);
        const float* tp = Tp + k * 12;    // per-lane gather, L2-resident (307 KB table)
        float4 q0 = *(const float4*)(tp);
        float4 q1 = *(const float4*)(tp + 4);
        float4 q2 = *(const float4*)(tp + 8);
        sv[0] += gk * q0.x; sv[1] += gk * q0.y; sv[2]  += gk * q0.z; sv[3]  += gk * q0.w;
        sv[4] += gk * q1.x; sv[5] += gk * q1.y; sv[6]  += gk * q1.z; sv[7]  += gk * q1.w;
        sv[8] += gk * q2.x; sv[9] += gk * q2.y; sv[10] += gk * q2.z; sv[11] += gk * q2.w;
    }

    const float isc = 1.0f / 64.0f;
    #pragma unroll
    for (int i = 0; i < 12; i++) sv[i] *= isc;

    // spherical harmonics (inline)
    const float S3  = 1.7320508075688772f;
    const float S15 = 3.8729833462074170f;
    const float S5  = 2.2360679774997896f;
    float sh1v[3], sh2v[5];
    sh1v[0] = S3 * y; sh1v[1] = S3 * z; sh1v[2] = S3 * x;
    sh2v[0] = S15 * x * y;
    sh2v[1] = S15 * y * z;
    sh2v[2] = 0.5f * S5 * (3.0f * z * z - 1.0f);
    sh2v[3] = S15 * x * z;
    sh2v[4] = 0.5f * S15 * (x * x - y * y);

    float* o = out + d * 36;
    #pragma unroll
    for (int w = 0; w < 4; w++) atomicAdd(o + w, sv[w]);
    #pragma unroll
    for (int w = 0; w < 4; w++) {
        float sw = sv[4 + w];
        #pragma unroll
        for (int jj = 0; jj < 3; jj++) atomicAdd(o + 4 + w * 3 + jj, sw * sh1v[jj]);
    }
    #pragma unroll
    for (int w = 0; w < 4; w++) {
        float sw = sv[8 + w];
        #pragma unroll
        for (int jj = 0; jj < 5; jj++) atomicAdd(o + 16 + w * 5 + jj, sw * sh2v[jj]);
    }
    atomicAdd(cnt + d, 1.0f);
}

// ---------------- K5: divide by per-node edge count ----------------------------------
__global__ void finalize_kernel(float* __restrict__ out, const float* __restrict__ cnt) {
    int i = blockIdx.x * 256 + threadIdx.x;
    if (i < N_NODES * 36) {
        float c = cnt[i / 36];
        out[i] = out[i] / fmaxf(c, 1.0f);
    }
}

extern "C" void kernel_launch(void* const* d_in, const int* in_sizes, int n_in,
                              void* d_out, int out_size, void* d_ws, size_t ws_size,
                              hipStream_t stream) {
    const float* pos    = (const float*)d_in[0];
    const int*   A      = (const int*)d_in[1];
    const int*   batch  = (const int*)d_in[2];
    const int*   esrc   = (const int*)d_in[3];
    const int*   edst   = (const int*)d_in[4];
    const float* shifts = (const float*)d_in[5];
    const float* cell   = (const float*)d_in[6];
    const float* emb    = (const float*)d_in[7];
    const float* fw1    = (const float*)d_in[8];
    const float* fb1    = (const float*)d_in[9];
    const float* fw2    = (const float*)d_in[10];
    const float* fb2    = (const float*)d_in[11];
    const float* fw3    = (const float*)d_in[12];
    const float* fb3    = (const float*)d_in[13];
    const float* fcw1   = (const float*)d_in[14];
    const float* fcw2   = (const float*)d_in[15];
    const float* fcw3   = (const float*)d_in[16];
    const float* fcw4   = (const float*)d_in[17];
    float* out = (float*)d_out;

    char* ws = (char*)d_ws;
    float* T      = (float*)(ws + OFF_T);
    float* w1t    = (float*)(ws + OFF_W1T);
    float* w2t    = (float*)(ws + OFF_W2T);
    float* w3t    = (float*)(ws + OFF_W3T);
    float* ai_tab = (float*)(ws + OFF_AI);
    float* cnt    = (float*)(ws + OFF_CNT);

    hipMemsetAsync(out, 0, (size_t)N_NODES * 36 * 4, stream);
    hipMemsetAsync(cnt, 0, (size_t)N_NODES * 4, stream);

    ai_table_kernel<<<10, 64, 0, stream>>>(emb, fw1, fb1, fw2, fb2, fw3, fb3, ai_tab);
    prep_kernel<<<(PREP_W3T_END + 255) / 256, 256, 0, stream>>>(fcw1, fcw2, fcw3, w1t, w2t, w3t);
    build_T_kernel<<<25, 256, 0, stream>>>(fcw4, ai_tab, T);
    edge_fused_kernel<<<N_EDGES / 256, 256, 0, stream>>>(
        pos, batch, esrc, edst, shifts, cell, A, w1t, w2t, w3t, T, out, cnt);
    finalize_kernel<<<(N_NODES * 36 + 255) / 256, 256, 0, stream>>>(out, cnt);
}

// Round 5
// 488.132 us; speedup vs baseline: 2.4494x; 1.2027x over previous
//
#include <hip/hip_runtime.h>
#include <math.h>

#define N_NODES 20000
#define N_EDGES 160000

// ws layout (bytes). ~350 KB.
static const size_t OFF_T   = 0;                                   // T [100][64][12] f32
static const size_t OFF_W1T = OFF_T   + (size_t)100 * 64 * 12 * 4; // w1T [64][16]
static const size_t OFF_W2T = OFF_W1T + (size_t)64 * 16 * 4;       // w2T [64][64]
static const size_t OFF_W3T = OFF_W2T + (size_t)64 * 64 * 4;       // w3T [64][64]
static const size_t OFF_AI  = OFF_W3T + (size_t)64 * 64 * 4;       // AiTable [10][8]
static const size_t OFF_CNT = OFF_AI + 512;                        // cnt [N_NODES] f32

#define PREP_W1T_END 1024                      // 64*16
#define PREP_W2T_END (PREP_W1T_END + 4096)     // 64*64
#define PREP_W3T_END (PREP_W2T_END + 4096)     // 64*64 -> total 9216

__device__ __forceinline__ float silu_f(float x) {
    return x / (1.0f + __expf(-x));
}

// ---------------- K1: node-type MLP table (10 types, Ai = 8 floats each) -------------
__global__ void ai_table_kernel(const float* __restrict__ emb,
                                const float* __restrict__ w1, const float* __restrict__ b1,
                                const float* __restrict__ w2, const float* __restrict__ b2,
                                const float* __restrict__ w3, const float* __restrict__ b3,
                                float* __restrict__ ai_out) {
    __shared__ float h1[64];
    __shared__ float h2[32];
    int t = blockIdx.x;
    int j = threadIdx.x;
    float acc = b1[j];
    #pragma unroll
    for (int i = 0; i < 16; i++) acc += emb[t * 16 + i] * w1[i * 64 + j];
    h1[j] = silu_f(acc);
    __syncthreads();
    if (j < 32) {
        float a2 = b2[j];
        #pragma unroll
        for (int i = 0; i < 64; i++) a2 += h1[i] * w2[i * 32 + j];
        h2[j] = silu_f(a2);
    }
    __syncthreads();
    if (j < 8) {
        float a3 = b3[j];
        #pragma unroll
        for (int i = 0; i < 32; i++) a3 += h2[i] * w3[i * 8 + j];
        ai_out[t * 8 + j] = a3;
    }
}

// ---------------- K2: weight transposes for the radial MLP ---------------------------
__global__ void prep_kernel(const float* __restrict__ fc_w1, const float* __restrict__ fc_w2,
                            const float* __restrict__ fc_w3,
                            float* __restrict__ w1t, float* __restrict__ w2t,
                            float* __restrict__ w3t) {
    int idx = blockIdx.x * 256 + threadIdx.x;
    if (idx < PREP_W1T_END) {
        int j = idx >> 4, i = idx & 15;
        w1t[j * 16 + i] = fc_w1[i * 64 + j];
    } else if (idx < PREP_W2T_END) {
        int t = idx - PREP_W1T_END; int j = t >> 6, i = t & 63;
        w2t[j * 64 + i] = fc_w2[i * 64 + j];
    } else if (idx < PREP_W3T_END) {
        int t = idx - PREP_W2T_END; int j = t >> 6, i = t & 63;
        w3t[j * 64 + i] = fc_w3[i * 64 + j];
    }
}

// ---------------- K2b: T table (pair-contracted fc_w4) -------------------------------
__global__ void build_T_kernel(const float* __restrict__ fc_w4,
                               const float* __restrict__ ai_tab,
                               float* __restrict__ T) {
    int idx = blockIdx.x * 256 + threadIdx.x;
    if (idx >= 6400) return;
    int pair = idx >> 6;          // 0..99
    int k = idx & 63;
    int ts = pair / 10, td = pair - ts * 10;

    float a[8], b[8];
    #pragma unroll
    for (int i = 0; i < 8; i++) a[i] = ai_tab[ts * 8 + i];
    #pragma unroll
    for (int i = 0; i < 8; i++) b[i] = ai_tab[td * 8 + i];

    float sv[12];
    #pragma unroll
    for (int i = 0; i < 12; i++) sv[i] = 0.0f;

    const float* wk = fc_w4 + k * 768;
    #pragma unroll 2
    for (int u = 0; u < 8; u++) {
        #pragma unroll
        for (int v = 0; v < 8; v++) {
            float ab = a[u] * b[v];
            const float* wp = wk + u * 32 + v * 4;
            float4 w0 = *(const float4*)(wp);
            float4 w1 = *(const float4*)(wp + 256);
            float4 w2 = *(const float4*)(wp + 512);
            sv[0] += ab * w0.x; sv[1] += ab * w0.y; sv[2]  += ab * w0.z; sv[3]  += ab * w0.w;
            sv[4] += ab * w1.x; sv[5] += ab * w1.y; sv[6]  += ab * w1.z; sv[7]  += ab * w1.w;
            sv[8] += ab * w2.x; sv[9] += ab * w2.y; sv[10] += ab * w2.z; sv[11] += ab * w2.w;
        }
    }
    float* tp = T + pair * 768 + k * 12;
    #pragma unroll
    for (int j = 0; j < 12; j++) tp[j] = sv[j];
}

// ---------------- K3: cooperative fused edge kernel ----------------------------------
// Block = 256 threads = 4 waves over a 64-edge tile. Wave w owns channels
// [16w,16w+16) of each layer; lane = edge. Activations via 16 KB LDS.
// Weight rows addressed via readfirstlane(wq) -> provably wave-uniform -> s_load.
__global__ __launch_bounds__(256) void edge_fused_kernel(
        const float* __restrict__ pos, const int* __restrict__ batch,
        const int* __restrict__ esrc, const int* __restrict__ edst,
        const float* __restrict__ shifts, const float* __restrict__ cell,
        const int* __restrict__ A,
        const float* __restrict__ w1t, const float* __restrict__ w2t,
        const float* __restrict__ w3t, const float* __restrict__ T,
        float* __restrict__ out, float* __restrict__ cnt) {
    __shared__ float smem[4096];              // 16 KB: act buffer [ch][64], later partials [4][12][64]
    int tid = threadIdx.x;
    int lane = tid & 63;
    int wq = __builtin_amdgcn_readfirstlane(tid >> 6);   // wave id 0..3, SGPR
    int e = blockIdx.x * 64 + lane;           // grid exact: 2500*64

    // ---- geometry (computed redundantly by all 4 waves; cheap, L1-hit loads) ----
    int s = esrc[e], d = edst[e];
    int gb = batch[s];
    float t0 = shifts[e * 3 + 0], t1 = shifts[e * 3 + 1], t2 = shifts[e * 3 + 2];
    const float* C = cell + gb * 9;
    float shx = t0 * C[0] + t1 * C[3] + t2 * C[6];
    float shy = t0 * C[1] + t1 * C[4] + t2 * C[7];
    float shz = t0 * C[2] + t1 * C[5] + t2 * C[8];
    float ex = pos[d * 3 + 0] - pos[s * 3 + 0] + shx;
    float ey = pos[d * 3 + 1] - pos[s * 3 + 1] + shy;
    float ez = pos[d * 3 + 2] - pos[s * 3 + 2] + shz;
    float r = sqrtf(ex * ex + ey * ey + ez * ez);
    float inv = 1.0f / fmaxf(r, 1e-9f);
    float x = ex * inv, y = ey * inv, z = ez * inv;

    // radial basis
    float rb[16];
    const float step = 5.0f / 17.0f;
    const float istep = 17.0f / 5.0f;
    const float rsc = 4.0f / 1.12f;
    #pragma unroll
    for (int i = 0; i < 16; i++) {
        float dd = (r - (float)(i + 1) * step) * istep;
        rb[i] = __expf(-dd * dd) * rsc;
    }

    // ---- L1: 16 -> 64, wave w computes channels [16wq,16wq+16) ----
    #pragma unroll
    for (int jj = 0; jj < 16; jj++) {
        const float* wr = w1t + (wq * 16 + jj) * 16;   // SGPR address
        float a0 = 0, a1 = 0, a2 = 0, a3 = 0;
        #pragma unroll
        for (int i = 0; i < 16; i += 4) {
            a0 += rb[i] * wr[i];         a1 += rb[i + 1] * wr[i + 1];
            a2 += rb[i + 2] * wr[i + 2]; a3 += rb[i + 3] * wr[i + 3];
        }
        smem[(wq * 16 + jj) * 64 + lane] = silu_f(((a0 + a1) + (a2 + a3)) * 0.25f);
    }
    __syncthreads();

    // ---- L2: 64 -> 64, chunked LDS reads (each h read once, reused 16x from regs) ----
    float acc[16];
    #pragma unroll
    for (int jj = 0; jj < 16; jj++) acc[jj] = 0.0f;
    #pragma unroll
    for (int c = 0; c < 4; c++) {
        float hc[16];
        #pragma unroll
        for (int i = 0; i < 16; i++) hc[i] = smem[(c * 16 + i) * 64 + lane];
        #pragma unroll
        for (int jj = 0; jj < 16; jj++) {
            const float* wr = w2t + (wq * 16 + jj) * 64 + c * 16;  // SGPR address
            #pragma unroll
            for (int i = 0; i < 16; i++) acc[jj] += hc[i] * wr[i];
        }
    }
    float hn[16];
    #pragma unroll
    for (int jj = 0; jj < 16; jj++) hn[jj] = silu_f(acc[jj] * 0.125f);
    __syncthreads();                                    // all L2 reads done
    #pragma unroll
    for (int jj = 0; jj < 16; jj++) smem[(wq * 16 + jj) * 64 + lane] = hn[jj];
    __syncthreads();

    // ---- L3: 64 -> 64 fused with T-matvec ----
    #pragma unroll
    for (int jj = 0; jj < 16; jj++) acc[jj] = 0.0f;
    #pragma unroll
    for (int c = 0; c < 4; c++) {
        float hc[16];
        #pragma unroll
        for (int i = 0; i < 16; i++) hc[i] = smem[(c * 16 + i) * 64 + lane];
        #pragma unroll
        for (int jj = 0; jj < 16; jj++) {
            const float* wr = w3t + (wq * 16 + jj) * 64 + c * 16;  // SGPR address
            #pragma unroll
            for (int i = 0; i < 16; i++) acc[jj] += hc[i] * wr[i];
        }
    }
    float gk[16];
    #pragma unroll
    for (int jj = 0; jj < 16; jj++) gk[jj] = silu_f(acc[jj] * 0.125f);

    int pair = A[s] * 10 + A[d];
    const float* Tp = T + pair * 768 + wq * 16 * 12;    // per-lane base, L2-resident

    float sv[12];
    #pragma unroll
    for (int i = 0; i < 12; i++) sv[i] = 0.0f;
    #pragma unroll
    for (int jj = 0; jj < 16; jj++) {
        const float* tp = Tp + jj * 12;
        float4 q0 = *(const float4*)(tp);
        float4 q1 = *(const float4*)(tp + 4);
        float4 q2 = *(const float4*)(tp + 8);
        float g = gk[jj];
        sv[0] += g * q0.x; sv[1] += g * q0.y; sv[2]  += g * q0.z; sv[3]  += g * q0.w;
        sv[4] += g * q1.x; sv[5] += g * q1.y; sv[6]  += g * q1.z; sv[7]  += g * q1.w;
        sv[8] += g * q2.x; sv[9] += g * q2.y; sv[10] += g * q2.z; sv[11] += g * q2.w;
    }
    __syncthreads();                                    // all L3 reads done; reuse smem for partials

    // partials [w][12][64] = 12 KB
    #pragma unroll
    for (int j = 0; j < 12; j++) smem[(wq * 12 + j) * 64 + lane] = sv[j];
    __syncthreads();

    // ---- reduction + epilogue: wave w owns output column w ----
    float s0 = 0.0f, s1 = 0.0f, s2 = 0.0f;
    #pragma unroll
    for (int p = 0; p < 4; p++) {
        s0 += smem[(p * 12 + wq + 0) * 64 + lane];
        s1 += smem[(p * 12 + wq + 4) * 64 + lane];
        s2 += smem[(p * 12 + wq + 8) * 64 + lane];
    }
    const float isc = 1.0f / 64.0f;
    s0 *= isc; s1 *= isc; s2 *= isc;

    const float S3  = 1.7320508075688772f;
    const float S15 = 3.8729833462074170f;
    const float S5  = 2.2360679774997896f;
    float sh1v[3], sh2v[5];
    sh1v[0] = S3 * y; sh1v[1] = S3 * z; sh1v[2] = S3 * x;
    sh2v[0] = S15 * x * y;
    sh2v[1] = S15 * y * z;
    sh2v[2] = 0.5f * S5 * (3.0f * z * z - 1.0f);
    sh2v[3] = S15 * x * z;
    sh2v[4] = 0.5f * S15 * (x * x - y * y);

    float* o = out + d * 36;
    atomicAdd(o + wq, s0);
    #pragma unroll
    for (int jj = 0; jj < 3; jj++) atomicAdd(o + 4 + wq * 3 + jj, s1 * sh1v[jj]);
    #pragma unroll
    for (int jj = 0; jj < 5; jj++) atomicAdd(o + 16 + wq * 5 + jj, s2 * sh2v[jj]);
    if (wq == 0) atomicAdd(cnt + d, 1.0f);
}

// ---------------- K5: divide by per-node edge count ----------------------------------
__global__ void finalize_kernel(float* __restrict__ out, const float* __restrict__ cnt) {
    int i = blockIdx.x * 256 + threadIdx.x;
    if (i < N_NODES * 36) {
        float c = cnt[i / 36];
        out[i] = out[i] / fmaxf(c, 1.0f);
    }
}

extern "C" void kernel_launch(void* const* d_in, const int* in_sizes, int n_in,
                              void* d_out, int out_size, void* d_ws, size_t ws_size,
                              hipStream_t stream) {
    const float* pos    = (const float*)d_in[0];
    const int*   A      = (const int*)d_in[1];
    const int*   batch  = (const int*)d_in[2];
    const int*   esrc   = (const int*)d_in[3];
    const int*   edst   = (const int*)d_in[4];
    const float* shifts = (const float*)d_in[5];
    const float* cell   = (const float*)d_in[6];
    const float* emb    = (const float*)d_in[7];
    const float* fw1    = (const float*)d_in[8];
    const float* fb1    = (const float*)d_in[9];
    const float* fw2    = (const float*)d_in[10];
    const float* fb2    = (const float*)d_in[11];
    const float* fw3    = (const float*)d_in[12];
    const float* fb3    = (const float*)d_in[13];
    const float* fcw1   = (const float*)d_in[14];
    const float* fcw2   = (const float*)d_in[15];
    const float* fcw3   = (const float*)d_in[16];
    const float* fcw4   = (const float*)d_in[17];
    float* out = (float*)d_out;

    char* ws = (char*)d_ws;
    float* T      = (float*)(ws + OFF_T);
    float* w1t    = (float*)(ws + OFF_W1T);
    float* w2t    = (float*)(ws + OFF_W2T);
    float* w3t    = (float*)(ws + OFF_W3T);
    float* ai_tab = (float*)(ws + OFF_AI);
    float* cnt    = (float*)(ws + OFF_CNT);

    hipMemsetAsync(out, 0, (size_t)N_NODES * 36 * 4, stream);
    hipMemsetAsync(cnt, 0, (size_t)N_NODES * 4, stream);

    ai_table_kernel<<<10, 64, 0, stream>>>(emb, fw1, fb1, fw2, fb2, fw3, fb3, ai_tab);
    prep_kernel<<<(PREP_W3T_END + 255) / 256, 256, 0, stream>>>(fcw1, fcw2, fcw3, w1t, w2t, w3t);
    build_T_kernel<<<25, 256, 0, stream>>>(fcw4, ai_tab, T);
    edge_fused_kernel<<<N_EDGES / 64, 256, 0, stream>>>(
        pos, batch, esrc, edst, shifts, cell, A, w1t, w2t, w3t, T, out, cnt);
    finalize_kernel<<<(N_NODES * 36 + 255) / 256, 256, 0, stream>>>(out, cnt);
}

// Round 6
// 311.885 us; speedup vs baseline: 3.8335x; 1.5651x over previous
//
#include <hip/hip_runtime.h>
#include <math.h>

#define N_NODES 20000
#define N_EDGES 160000

// ws layout (bytes). ~25 MB.
static const size_t OFF_EF  = 0;                                    // ef [E][36] f32
static const size_t OFF_T   = OFF_EF  + (size_t)N_EDGES * 36 * 4;   // T [100][64][12] f32
static const size_t OFF_W1T = OFF_T   + (size_t)100 * 64 * 12 * 4;  // w1T [64][16]
static const size_t OFF_W2T = OFF_W1T + (size_t)64 * 16 * 4;        // w2T [64][64]
static const size_t OFF_W3T = OFF_W2T + (size_t)64 * 64 * 4;        // w3T [64][64]
static const size_t OFF_AI  = OFF_W3T + (size_t)64 * 64 * 4;        // AiTable [10][8]
static const size_t OFF_NOFF= OFF_AI  + 512;                        // node_off [N+1] int
static const size_t OFF_NCNT= OFF_NOFF+ (size_t)(N_NODES + 1) * 4;  // cnt_i [N] int
static const size_t OFF_NCUR= OFF_NCNT+ (size_t)N_NODES * 4;        // node_cur [N] int
static const size_t OFF_CSR = OFF_NCUR+ (size_t)N_NODES * 4;        // csr_edges [E] int

#define PREP_W1T_END 1024
#define PREP_W2T_END (PREP_W1T_END + 4096)
#define PREP_W3T_END (PREP_W2T_END + 4096)

__device__ __forceinline__ float silu_f(float x) {
    return x / (1.0f + __expf(-x));
}

// ---------------- K1: node-type MLP table ------------------------------------------
__global__ void ai_table_kernel(const float* __restrict__ emb,
                                const float* __restrict__ w1, const float* __restrict__ b1,
                                const float* __restrict__ w2, const float* __restrict__ b2,
                                const float* __restrict__ w3, const float* __restrict__ b3,
                                float* __restrict__ ai_out) {
    __shared__ float h1[64];
    __shared__ float h2[32];
    int t = blockIdx.x;
    int j = threadIdx.x;
    float acc = b1[j];
    #pragma unroll
    for (int i = 0; i < 16; i++) acc += emb[t * 16 + i] * w1[i * 64 + j];
    h1[j] = silu_f(acc);
    __syncthreads();
    if (j < 32) {
        float a2 = b2[j];
        #pragma unroll
        for (int i = 0; i < 64; i++) a2 += h1[i] * w2[i * 32 + j];
        h2[j] = silu_f(a2);
    }
    __syncthreads();
    if (j < 8) {
        float a3 = b3[j];
        #pragma unroll
        for (int i = 0; i < 32; i++) a3 += h2[i] * w3[i * 8 + j];
        ai_out[t * 8 + j] = a3;
    }
}

// ---------------- K2: weight transposes --------------------------------------------
__global__ void prep_kernel(const float* __restrict__ fc_w1, const float* __restrict__ fc_w2,
                            const float* __restrict__ fc_w3,
                            float* __restrict__ w1t, float* __restrict__ w2t,
                            float* __restrict__ w3t) {
    int idx = blockIdx.x * 256 + threadIdx.x;
    if (idx < PREP_W1T_END) {
        int j = idx >> 4, i = idx & 15;
        w1t[j * 16 + i] = fc_w1[i * 64 + j];
    } else if (idx < PREP_W2T_END) {
        int t = idx - PREP_W1T_END; int j = t >> 6, i = t & 63;
        w2t[j * 64 + i] = fc_w2[i * 64 + j];
    } else if (idx < PREP_W3T_END) {
        int t = idx - PREP_W2T_END; int j = t >> 6, i = t & 63;
        w3t[j * 64 + i] = fc_w3[i * 64 + j];
    }
}

// ---------------- K2b: T table (pair-contracted fc_w4) ------------------------------
__global__ void build_T_kernel(const float* __restrict__ fc_w4,
                               const float* __restrict__ ai_tab,
                               float* __restrict__ T) {
    int idx = blockIdx.x * 256 + threadIdx.x;
    if (idx >= 6400) return;
    int pair = idx >> 6;
    int k = idx & 63;
    int ts = pair / 10, td = pair - ts * 10;

    float a[8], b[8];
    #pragma unroll
    for (int i = 0; i < 8; i++) a[i] = ai_tab[ts * 8 + i];
    #pragma unroll
    for (int i = 0; i < 8; i++) b[i] = ai_tab[td * 8 + i];

    float sv[12];
    #pragma unroll
    for (int i = 0; i < 12; i++) sv[i] = 0.0f;

    const float* wk = fc_w4 + k * 768;
    #pragma unroll 2
    for (int u = 0; u < 8; u++) {
        #pragma unroll
        for (int v = 0; v < 8; v++) {
            float ab = a[u] * b[v];
            const float* wp = wk + u * 32 + v * 4;
            float4 w0 = *(const float4*)(wp);
            float4 w1 = *(const float4*)(wp + 256);
            float4 w2 = *(const float4*)(wp + 512);
            sv[0] += ab * w0.x; sv[1] += ab * w0.y; sv[2]  += ab * w0.z; sv[3]  += ab * w0.w;
            sv[4] += ab * w1.x; sv[5] += ab * w1.y; sv[6]  += ab * w1.z; sv[7]  += ab * w1.w;
            sv[8] += ab * w2.x; sv[9] += ab * w2.y; sv[10] += ab * w2.z; sv[11] += ab * w2.w;
        }
    }
    float* tp = T + pair * 768 + k * 12;
    #pragma unroll
    for (int j = 0; j < 12; j++) tp[j] = sv[j];
}

// ---------------- CSR build: histogram / scan / scatter -----------------------------
__global__ void hist_kernel(const int* __restrict__ edst, int* __restrict__ cnt_i) {
    int e = blockIdx.x * 256 + threadIdx.x;
    if (e < N_EDGES) atomicAdd(&cnt_i[edst[e]], 1);
}

// single block, 1024 threads; each owns 20 nodes. Hillis-Steele over 1024 partials.
__global__ __launch_bounds__(1024) void scan_kernel(const int* __restrict__ cnt_i,
                                                    int* __restrict__ node_off) {
    __shared__ int part[1024];
    int t = threadIdx.x;
    int base = t * 20;
    int s = 0;
    #pragma unroll 4
    for (int i = 0; i < 20; i++) {
        int n = base + i;
        if (n < N_NODES) s += cnt_i[n];
    }
    part[t] = s;
    __syncthreads();
    for (int off = 1; off < 1024; off <<= 1) {
        int v = part[t];
        int add = (t >= off) ? part[t - off] : 0;
        __syncthreads();
        part[t] = v + add;
        __syncthreads();
    }
    int run = (t == 0) ? 0 : part[t - 1];   // exclusive
    #pragma unroll 4
    for (int i = 0; i < 20; i++) {
        int n = base + i;
        if (n < N_NODES) { node_off[n] = run; run += cnt_i[n]; }
    }
    if (t == 1023) node_off[N_NODES] = run;
}

__global__ void scatter_kernel(const int* __restrict__ edst,
                               const int* __restrict__ node_off,
                               int* __restrict__ node_cur,
                               int* __restrict__ csr_edges) {
    int e = blockIdx.x * 256 + threadIdx.x;
    if (e >= N_EDGES) return;
    int d = edst[e];
    int slot = atomicAdd(&node_cur[d], 1);
    csr_edges[node_off[d] + slot] = e;
}

// ---------------- K3: cooperative fused edge kernel (stores, no atomics) ------------
__global__ __launch_bounds__(256) void edge_fused_kernel(
        const float* __restrict__ pos, const int* __restrict__ batch,
        const int* __restrict__ esrc, const int* __restrict__ edst,
        const float* __restrict__ shifts, const float* __restrict__ cell,
        const int* __restrict__ A,
        const float* __restrict__ w1t, const float* __restrict__ w2t,
        const float* __restrict__ w3t, const float* __restrict__ T,
        float* __restrict__ ef) {
    __shared__ float smem[4096];
    int tid = threadIdx.x;
    int lane = tid & 63;
    int wq = __builtin_amdgcn_readfirstlane(tid >> 6);
    int e = blockIdx.x * 64 + lane;

    int s = esrc[e], d = edst[e];
    int gb = batch[s];
    float t0 = shifts[e * 3 + 0], t1 = shifts[e * 3 + 1], t2 = shifts[e * 3 + 2];
    const float* C = cell + gb * 9;
    float shx = t0 * C[0] + t1 * C[3] + t2 * C[6];
    float shy = t0 * C[1] + t1 * C[4] + t2 * C[7];
    float shz = t0 * C[2] + t1 * C[5] + t2 * C[8];
    float ex = pos[d * 3 + 0] - pos[s * 3 + 0] + shx;
    float ey = pos[d * 3 + 1] - pos[s * 3 + 1] + shy;
    float ez = pos[d * 3 + 2] - pos[s * 3 + 2] + shz;
    float r = sqrtf(ex * ex + ey * ey + ez * ez);
    float inv = 1.0f / fmaxf(r, 1e-9f);
    float x = ex * inv, y = ey * inv, z = ez * inv;

    float rb[16];
    const float step = 5.0f / 17.0f;
    const float istep = 17.0f / 5.0f;
    const float rsc = 4.0f / 1.12f;
    #pragma unroll
    for (int i = 0; i < 16; i++) {
        float dd = (r - (float)(i + 1) * step) * istep;
        rb[i] = __expf(-dd * dd) * rsc;
    }

    // L1: 16 -> 64
    #pragma unroll
    for (int jj = 0; jj < 16; jj++) {
        const float* wr = w1t + (wq * 16 + jj) * 16;
        float a0 = 0, a1 = 0, a2 = 0, a3 = 0;
        #pragma unroll
        for (int i = 0; i < 16; i += 4) {
            a0 += rb[i] * wr[i];         a1 += rb[i + 1] * wr[i + 1];
            a2 += rb[i + 2] * wr[i + 2]; a3 += rb[i + 3] * wr[i + 3];
        }
        smem[(wq * 16 + jj) * 64 + lane] = silu_f(((a0 + a1) + (a2 + a3)) * 0.25f);
    }
    __syncthreads();

    // L2: 64 -> 64
    float acc[16];
    #pragma unroll
    for (int jj = 0; jj < 16; jj++) acc[jj] = 0.0f;
    #pragma unroll
    for (int c = 0; c < 4; c++) {
        float hc[16];
        #pragma unroll
        for (int i = 0; i < 16; i++) hc[i] = smem[(c * 16 + i) * 64 + lane];
        #pragma unroll
        for (int jj = 0; jj < 16; jj++) {
            const float* wr = w2t + (wq * 16 + jj) * 64 + c * 16;
            #pragma unroll
            for (int i = 0; i < 16; i++) acc[jj] += hc[i] * wr[i];
        }
    }
    float hn[16];
    #pragma unroll
    for (int jj = 0; jj < 16; jj++) hn[jj] = silu_f(acc[jj] * 0.125f);
    __syncthreads();
    #pragma unroll
    for (int jj = 0; jj < 16; jj++) smem[(wq * 16 + jj) * 64 + lane] = hn[jj];
    __syncthreads();

    // L3 fused with T-matvec
    #pragma unroll
    for (int jj = 0; jj < 16; jj++) acc[jj] = 0.0f;
    #pragma unroll
    for (int c = 0; c < 4; c++) {
        float hc[16];
        #pragma unroll
        for (int i = 0; i < 16; i++) hc[i] = smem[(c * 16 + i) * 64 + lane];
        #pragma unroll
        for (int jj = 0; jj < 16; jj++) {
            const float* wr = w3t + (wq * 16 + jj) * 64 + c * 16;
            #pragma unroll
            for (int i = 0; i < 16; i++) acc[jj] += hc[i] * wr[i];
        }
    }
    float gk[16];
    #pragma unroll
    for (int jj = 0; jj < 16; jj++) gk[jj] = silu_f(acc[jj] * 0.125f);

    int pair = A[s] * 10 + A[d];
    const float* Tp = T + pair * 768 + wq * 16 * 12;

    float sv[12];
    #pragma unroll
    for (int i = 0; i < 12; i++) sv[i] = 0.0f;
    #pragma unroll
    for (int jj = 0; jj < 16; jj++) {
        const float* tp = Tp + jj * 12;
        float4 q0 = *(const float4*)(tp);
        float4 q1 = *(const float4*)(tp + 4);
        float4 q2 = *(const float4*)(tp + 8);
        float g = gk[jj];
        sv[0] += g * q0.x; sv[1] += g * q0.y; sv[2]  += g * q0.z; sv[3]  += g * q0.w;
        sv[4] += g * q1.x; sv[5] += g * q1.y; sv[6]  += g * q1.z; sv[7]  += g * q1.w;
        sv[8] += g * q2.x; sv[9] += g * q2.y; sv[10] += g * q2.z; sv[11] += g * q2.w;
    }
    __syncthreads();

    #pragma unroll
    for (int j = 0; j < 12; j++) smem[(wq * 12 + j) * 64 + lane] = sv[j];
    __syncthreads();

    float s0 = 0.0f, s1 = 0.0f, s2 = 0.0f;
    #pragma unroll
    for (int p = 0; p < 4; p++) {
        s0 += smem[(p * 12 + wq + 0) * 64 + lane];
        s1 += smem[(p * 12 + wq + 4) * 64 + lane];
        s2 += smem[(p * 12 + wq + 8) * 64 + lane];
    }
    const float isc = 1.0f / 64.0f;
    s0 *= isc; s1 *= isc; s2 *= isc;

    const float S3  = 1.7320508075688772f;
    const float S15 = 3.8729833462074170f;
    const float S5  = 2.2360679774997896f;
    float sh1v[3], sh2v[5];
    sh1v[0] = S3 * y; sh1v[1] = S3 * z; sh1v[2] = S3 * x;
    sh2v[0] = S15 * x * y;
    sh2v[1] = S15 * y * z;
    sh2v[2] = 0.5f * S5 * (3.0f * z * z - 1.0f);
    sh2v[3] = S15 * x * z;
    sh2v[4] = 0.5f * S15 * (x * x - y * y);

    // plain stores into ef[e][36]; L2 write-combines rows (no atomics, no vmcnt pileup)
    float* o = ef + (size_t)e * 36;
    o[wq] = s0;
    #pragma unroll
    for (int jj = 0; jj < 3; jj++) o[4 + wq * 3 + jj] = s1 * sh1v[jj];
    #pragma unroll
    for (int jj = 0; jj < 5; jj++) o[16 + wq * 5 + jj] = s2 * sh2v[jj];
}

// ---------------- K4: gather + mean -------------------------------------------------
__global__ void gather_kernel(const float* __restrict__ ef,
                              const int* __restrict__ node_off,
                              const int* __restrict__ csr_edges,
                              float* __restrict__ out) {
    int idx = blockIdx.x * 256 + threadIdx.x;
    if (idx >= N_NODES * 36) return;
    int n = idx / 36;
    int ch = idx - n * 36;
    int beg = node_off[n], end = node_off[n + 1];
    float s = 0.0f;
    for (int p = beg; p < end; p++) {
        int eid = csr_edges[p];                     // broadcast across the node's 36 lanes
        s += ef[(size_t)eid * 36 + ch];             // 144B contiguous per edge -> coalesced
    }
    float c = fmaxf((float)(end - beg), 1.0f);
    out[idx] = s / c;
}

extern "C" void kernel_launch(void* const* d_in, const int* in_sizes, int n_in,
                              void* d_out, int out_size, void* d_ws, size_t ws_size,
                              hipStream_t stream) {
    const float* pos    = (const float*)d_in[0];
    const int*   A      = (const int*)d_in[1];
    const int*   batch  = (const int*)d_in[2];
    const int*   esrc   = (const int*)d_in[3];
    const int*   edst   = (const int*)d_in[4];
    const float* shifts = (const float*)d_in[5];
    const float* cell   = (const float*)d_in[6];
    const float* emb    = (const float*)d_in[7];
    const float* fw1    = (const float*)d_in[8];
    const float* fb1    = (const float*)d_in[9];
    const float* fw2    = (const float*)d_in[10];
    const float* fb2    = (const float*)d_in[11];
    const float* fw3    = (const float*)d_in[12];
    const float* fb3    = (const float*)d_in[13];
    const float* fcw1   = (const float*)d_in[14];
    const float* fcw2   = (const float*)d_in[15];
    const float* fcw3   = (const float*)d_in[16];
    const float* fcw4   = (const float*)d_in[17];
    float* out = (float*)d_out;

    char* ws = (char*)d_ws;
    float* ef      = (float*)(ws + OFF_EF);
    float* T       = (float*)(ws + OFF_T);
    float* w1t     = (float*)(ws + OFF_W1T);
    float* w2t     = (float*)(ws + OFF_W2T);
    float* w3t     = (float*)(ws + OFF_W3T);
    float* ai_tab  = (float*)(ws + OFF_AI);
    int*   node_off= (int*)(ws + OFF_NOFF);
    int*   cnt_i   = (int*)(ws + OFF_NCNT);
    int*   node_cur= (int*)(ws + OFF_NCUR);
    int*   csr     = (int*)(ws + OFF_CSR);

    hipMemsetAsync(cnt_i, 0, (size_t)N_NODES * 4, stream);
    hipMemsetAsync(node_cur, 0, (size_t)N_NODES * 4, stream);

    ai_table_kernel<<<10, 64, 0, stream>>>(emb, fw1, fb1, fw2, fb2, fw3, fb3, ai_tab);
    prep_kernel<<<(PREP_W3T_END + 255) / 256, 256, 0, stream>>>(fcw1, fcw2, fcw3, w1t, w2t, w3t);
    build_T_kernel<<<25, 256, 0, stream>>>(fcw4, ai_tab, T);
    hist_kernel<<<(N_EDGES + 255) / 256, 256, 0, stream>>>(edst, cnt_i);
    scan_kernel<<<1, 1024, 0, stream>>>(cnt_i, node_off);
    scatter_kernel<<<(N_EDGES + 255) / 256, 256, 0, stream>>>(edst, node_off, node_cur, csr);
    edge_fused_kernel<<<N_EDGES / 64, 256, 0, stream>>>(
        pos, batch, esrc, edst, shifts, cell, A, w1t, w2t, w3t, T, ef);
    gather_kernel<<<(N_NODES * 36 + 255) / 256, 256, 0, stream>>>(ef, node_off, csr, out);
}

// Round 7
// 301.054 us; speedup vs baseline: 3.9714x; 1.0360x over previous
//
#include <hip/hip_runtime.h>
#include <math.h>

#define N_NODES 20000
#define N_EDGES 160000

// ws layout (bytes). ~25 MB.
static const size_t OFF_EF  = 0;                                    // ef [E][36] f32 (CSR-ordered rows)
static const size_t OFF_T   = OFF_EF  + (size_t)N_EDGES * 36 * 4;   // T [100][64][12] f32
static const size_t OFF_W1T = OFF_T   + (size_t)100 * 64 * 12 * 4;  // w1T [64][16]
static const size_t OFF_W2T = OFF_W1T + (size_t)64 * 16 * 4;        // w2T [64][64]
static const size_t OFF_W3T = OFF_W2T + (size_t)64 * 64 * 4;        // w3T [64][64]
static const size_t OFF_AI  = OFF_W3T + (size_t)64 * 64 * 4;        // AiTable [10][8]
static const size_t OFF_NOFF= OFF_AI  + 512;                        // node_off [N+1] int
static const size_t OFF_NCNT= OFF_NOFF+ (size_t)(N_NODES + 1) * 4;  // cnt_i [N] int   (zeroed)
static const size_t OFF_NCUR= OFF_NCNT+ (size_t)N_NODES * 4;        // node_cur [N] int (zeroed, contiguous w/ cnt_i)
static const size_t OFF_CSR = OFF_NCUR+ (size_t)N_NODES * 4;        // csr_edges [E] int

#define PREP_W1T_END 1024
#define PREP_W2T_END (PREP_W1T_END + 4096)
#define PREP_W3T_END (PREP_W2T_END + 4096)

// mega_prep grid split: blocks [0,25) T-build, [25,61) transposes, [61,686) histogram
#define MEGA_T_BLOCKS    25
#define MEGA_PREP_BLOCKS 36
#define MEGA_HIST_BLOCKS 625
#define MEGA_GRID (MEGA_T_BLOCKS + MEGA_PREP_BLOCKS + MEGA_HIST_BLOCKS)

__device__ __forceinline__ float silu_f(float x) {
    return x / (1.0f + __expf(-x));
}

// ---------------- K1: node-type MLP table ------------------------------------------
__global__ void ai_table_kernel(const float* __restrict__ emb,
                                const float* __restrict__ w1, const float* __restrict__ b1,
                                const float* __restrict__ w2, const float* __restrict__ b2,
                                const float* __restrict__ w3, const float* __restrict__ b3,
                                float* __restrict__ ai_out) {
    __shared__ float h1[64];
    __shared__ float h2[32];
    int t = blockIdx.x;
    int j = threadIdx.x;
    float acc = b1[j];
    #pragma unroll
    for (int i = 0; i < 16; i++) acc += emb[t * 16 + i] * w1[i * 64 + j];
    h1[j] = silu_f(acc);
    __syncthreads();
    if (j < 32) {
        float a2 = b2[j];
        #pragma unroll
        for (int i = 0; i < 64; i++) a2 += h1[i] * w2[i * 32 + j];
        h2[j] = silu_f(a2);
    }
    __syncthreads();
    if (j < 8) {
        float a3 = b3[j];
        #pragma unroll
        for (int i = 0; i < 32; i++) a3 += h2[i] * w3[i * 8 + j];
        ai_out[t * 8 + j] = a3;
    }
}

// ---------------- K2: mega-prep — T-build + transposes + histogram in one dispatch ---
__global__ void mega_prep_kernel(const float* __restrict__ fc_w1, const float* __restrict__ fc_w2,
                                 const float* __restrict__ fc_w3, const float* __restrict__ fc_w4,
                                 const float* __restrict__ ai_tab, const int* __restrict__ edst,
                                 float* __restrict__ w1t, float* __restrict__ w2t,
                                 float* __restrict__ w3t, float* __restrict__ T,
                                 int* __restrict__ cnt_i) {
    int b = blockIdx.x;
    int tid = threadIdx.x;
    if (b < MEGA_T_BLOCKS) {
        // ---- T[pair][k][12] build ----
        int idx = b * 256 + tid;
        if (idx >= 6400) return;
        int pair = idx >> 6;
        int k = idx & 63;
        int ts = pair / 10, td = pair - ts * 10;

        float a[8], bb[8];
        #pragma unroll
        for (int i = 0; i < 8; i++) a[i] = ai_tab[ts * 8 + i];
        #pragma unroll
        for (int i = 0; i < 8; i++) bb[i] = ai_tab[td * 8 + i];

        float sv[12];
        #pragma unroll
        for (int i = 0; i < 12; i++) sv[i] = 0.0f;

        const float* wk = fc_w4 + k * 768;
        #pragma unroll 2
        for (int u = 0; u < 8; u++) {
            #pragma unroll
            for (int v = 0; v < 8; v++) {
                float ab = a[u] * bb[v];
                const float* wp = wk + u * 32 + v * 4;
                float4 w0 = *(const float4*)(wp);
                float4 w1 = *(const float4*)(wp + 256);
                float4 w2 = *(const float4*)(wp + 512);
                sv[0] += ab * w0.x; sv[1] += ab * w0.y; sv[2]  += ab * w0.z; sv[3]  += ab * w0.w;
                sv[4] += ab * w1.x; sv[5] += ab * w1.y; sv[6]  += ab * w1.z; sv[7]  += ab * w1.w;
                sv[8] += ab * w2.x; sv[9] += ab * w2.y; sv[10] += ab * w2.z; sv[11] += ab * w2.w;
            }
        }
        float* tp = T + pair * 768 + k * 12;
        #pragma unroll
        for (int j = 0; j < 12; j++) tp[j] = sv[j];
    } else if (b < MEGA_T_BLOCKS + MEGA_PREP_BLOCKS) {
        // ---- weight transposes ----
        int idx = (b - MEGA_T_BLOCKS) * 256 + tid;
        if (idx < PREP_W1T_END) {
            int j = idx >> 4, i = idx & 15;
            w1t[j * 16 + i] = fc_w1[i * 64 + j];
        } else if (idx < PREP_W2T_END) {
            int t = idx - PREP_W1T_END; int j = t >> 6, i = t & 63;
            w2t[j * 64 + i] = fc_w2[i * 64 + j];
        } else if (idx < PREP_W3T_END) {
            int t = idx - PREP_W2T_END; int j = t >> 6, i = t & 63;
            w3t[j * 64 + i] = fc_w3[i * 64 + j];
        }
    } else {
        // ---- histogram of edge_dst ----
        int e = (b - MEGA_T_BLOCKS - MEGA_PREP_BLOCKS) * 256 + tid;
        if (e < N_EDGES) atomicAdd(&cnt_i[edst[e]], 1);
    }
}

// ---------------- scan: single block, exclusive prefix over 20000 counts -------------
__global__ __launch_bounds__(1024) void scan_kernel(const int* __restrict__ cnt_i,
                                                    int* __restrict__ node_off) {
    __shared__ int part[1024];
    int t = threadIdx.x;
    int base = t * 20;
    int s = 0;
    #pragma unroll 4
    for (int i = 0; i < 20; i++) {
        int n = base + i;
        if (n < N_NODES) s += cnt_i[n];
    }
    part[t] = s;
    __syncthreads();
    for (int off = 1; off < 1024; off <<= 1) {
        int v = part[t];
        int add = (t >= off) ? part[t - off] : 0;
        __syncthreads();
        part[t] = v + add;
        __syncthreads();
    }
    int run = (t == 0) ? 0 : part[t - 1];   // exclusive
    #pragma unroll 4
    for (int i = 0; i < 20; i++) {
        int n = base + i;
        if (n < N_NODES) { node_off[n] = run; run += cnt_i[n]; }
    }
    if (t == 1023) node_off[N_NODES] = run;
}

__global__ void scatter_kernel(const int* __restrict__ edst,
                               const int* __restrict__ node_off,
                               int* __restrict__ node_cur,
                               int* __restrict__ csr_edges) {
    int e = blockIdx.x * 256 + threadIdx.x;
    if (e >= N_EDGES) return;
    int d = edst[e];
    int slot = atomicAdd(&node_cur[d], 1);
    csr_edges[node_off[d] + slot] = e;
}

// ---------------- K3: cooperative fused edge kernel, CSR-ordered output -------------
// Block = 256 threads = 4 waves over a 64-position CSR tile. Wave w owns channels
// [16w,16w+16); lane = CSR position p. Reads eid = csr_edges[p], writes ef[p][36]
// so the downstream gather is a contiguous stream per node.
__global__ __launch_bounds__(256) void edge_fused_kernel(
        const float* __restrict__ pos, const int* __restrict__ batch,
        const int* __restrict__ esrc, const int* __restrict__ edst,
        const float* __restrict__ shifts, const float* __restrict__ cell,
        const int* __restrict__ A, const int* __restrict__ csr_edges,
        const float* __restrict__ w1t, const float* __restrict__ w2t,
        const float* __restrict__ w3t, const float* __restrict__ T,
        float* __restrict__ ef) {
    __shared__ float smem[4096];
    int tid = threadIdx.x;
    int lane = tid & 63;
    int wq = __builtin_amdgcn_readfirstlane(tid >> 6);
    int p = blockIdx.x * 64 + lane;
    int e = csr_edges[p];                      // coalesced read; per-edge loads below are L2 gathers

    int s = esrc[e], d = edst[e];
    int gb = batch[s];
    float t0 = shifts[e * 3 + 0], t1 = shifts[e * 3 + 1], t2 = shifts[e * 3 + 2];
    const float* C = cell + gb * 9;
    float shx = t0 * C[0] + t1 * C[3] + t2 * C[6];
    float shy = t0 * C[1] + t1 * C[4] + t2 * C[7];
    float shz = t0 * C[2] + t1 * C[5] + t2 * C[8];
    float ex = pos[d * 3 + 0] - pos[s * 3 + 0] + shx;
    float ey = pos[d * 3 + 1] - pos[s * 3 + 1] + shy;
    float ez = pos[d * 3 + 2] - pos[s * 3 + 2] + shz;
    float r = sqrtf(ex * ex + ey * ey + ez * ez);
    float inv = 1.0f / fmaxf(r, 1e-9f);
    float x = ex * inv, y = ey * inv, z = ez * inv;

    float rb[16];
    const float step = 5.0f / 17.0f;
    const float istep = 17.0f / 5.0f;
    const float rsc = 4.0f / 1.12f;
    #pragma unroll
    for (int i = 0; i < 16; i++) {
        float dd = (r - (float)(i + 1) * step) * istep;
        rb[i] = __expf(-dd * dd) * rsc;
    }

    // L1: 16 -> 64
    #pragma unroll
    for (int jj = 0; jj < 16; jj++) {
        const float* wr = w1t + (wq * 16 + jj) * 16;
        float a0 = 0, a1 = 0, a2 = 0, a3 = 0;
        #pragma unroll
        for (int i = 0; i < 16; i += 4) {
            a0 += rb[i] * wr[i];         a1 += rb[i + 1] * wr[i + 1];
            a2 += rb[i + 2] * wr[i + 2]; a3 += rb[i + 3] * wr[i + 3];
        }
        smem[(wq * 16 + jj) * 64 + lane] = silu_f(((a0 + a1) + (a2 + a3)) * 0.25f);
    }
    __syncthreads();

    // L2: 64 -> 64
    float acc[16];
    #pragma unroll
    for (int jj = 0; jj < 16; jj++) acc[jj] = 0.0f;
    #pragma unroll
    for (int c = 0; c < 4; c++) {
        float hc[16];
        #pragma unroll
        for (int i = 0; i < 16; i++) hc[i] = smem[(c * 16 + i) * 64 + lane];
        #pragma unroll
        for (int jj = 0; jj < 16; jj++) {
            const float* wr = w2t + (wq * 16 + jj) * 64 + c * 16;
            #pragma unroll
            for (int i = 0; i < 16; i++) acc[jj] += hc[i] * wr[i];
        }
    }
    float hn[16];
    #pragma unroll
    for (int jj = 0; jj < 16; jj++) hn[jj] = silu_f(acc[jj] * 0.125f);
    __syncthreads();
    #pragma unroll
    for (int jj = 0; jj < 16; jj++) smem[(wq * 16 + jj) * 64 + lane] = hn[jj];
    __syncthreads();

    // L3 fused with T-matvec
    #pragma unroll
    for (int jj = 0; jj < 16; jj++) acc[jj] = 0.0f;
    #pragma unroll
    for (int c = 0; c < 4; c++) {
        float hc[16];
        #pragma unroll
        for (int i = 0; i < 16; i++) hc[i] = smem[(c * 16 + i) * 64 + lane];
        #pragma unroll
        for (int jj = 0; jj < 16; jj++) {
            const float* wr = w3t + (wq * 16 + jj) * 64 + c * 16;
            #pragma unroll
            for (int i = 0; i < 16; i++) acc[jj] += hc[i] * wr[i];
        }
    }
    float gk[16];
    #pragma unroll
    for (int jj = 0; jj < 16; jj++) gk[jj] = silu_f(acc[jj] * 0.125f);

    int pair = A[s] * 10 + A[d];
    const float* Tp = T + pair * 768 + wq * 16 * 12;

    float sv[12];
    #pragma unroll
    for (int i = 0; i < 12; i++) sv[i] = 0.0f;
    #pragma unroll
    for (int jj = 0; jj < 16; jj++) {
        const float* tp = Tp + jj * 12;
        float4 q0 = *(const float4*)(tp);
        float4 q1 = *(const float4*)(tp + 4);
        float4 q2 = *(const float4*)(tp + 8);
        float g = gk[jj];
        sv[0] += g * q0.x; sv[1] += g * q0.y; sv[2]  += g * q0.z; sv[3]  += g * q0.w;
        sv[4] += g * q1.x; sv[5] += g * q1.y; sv[6]  += g * q1.z; sv[7]  += g * q1.w;
        sv[8] += g * q2.x; sv[9] += g * q2.y; sv[10] += g * q2.z; sv[11] += g * q2.w;
    }
    __syncthreads();

    #pragma unroll
    for (int j = 0; j < 12; j++) smem[(wq * 12 + j) * 64 + lane] = sv[j];
    __syncthreads();

    float s0 = 0.0f, s1 = 0.0f, s2 = 0.0f;
    #pragma unroll
    for (int q = 0; q < 4; q++) {
        s0 += smem[(q * 12 + wq + 0) * 64 + lane];
        s1 += smem[(q * 12 + wq + 4) * 64 + lane];
        s2 += smem[(q * 12 + wq + 8) * 64 + lane];
    }
    const float isc = 1.0f / 64.0f;
    s0 *= isc; s1 *= isc; s2 *= isc;

    const float S3  = 1.7320508075688772f;
    const float S15 = 3.8729833462074170f;
    const float S5  = 2.2360679774997896f;
    float sh1v[3], sh2v[5];
    sh1v[0] = S3 * y; sh1v[1] = S3 * z; sh1v[2] = S3 * x;
    sh2v[0] = S15 * x * y;
    sh2v[1] = S15 * y * z;
    sh2v[2] = 0.5f * S5 * (3.0f * z * z - 1.0f);
    sh2v[3] = S15 * x * z;
    sh2v[4] = 0.5f * S15 * (x * x - y * y);

    // plain stores into CSR-ordered ef[p][36]
    float* o = ef + (size_t)p * 36;
    o[wq] = s0;
    #pragma unroll
    for (int jj = 0; jj < 3; jj++) o[4 + wq * 3 + jj] = s1 * sh1v[jj];
    #pragma unroll
    for (int jj = 0; jj < 5; jj++) o[16 + wq * 5 + jj] = s2 * sh2v[jj];
}

// ---------------- K4: gather + mean (contiguous stream per node) ---------------------
__global__ void gather_kernel(const float* __restrict__ ef,
                              const int* __restrict__ node_off,
                              float* __restrict__ out) {
    int idx = blockIdx.x * 256 + threadIdx.x;
    if (idx >= N_NODES * 36) return;
    int n = idx / 36;
    int ch = idx - n * 36;
    int beg = node_off[n], end = node_off[n + 1];
    float s = 0.0f;
    for (int p = beg; p < end; p++) {
        s += ef[(size_t)p * 36 + ch];   // sequential rows; 144B contiguous across the node's lanes
    }
    float c = fmaxf((float)(end - beg), 1.0f);
    out[idx] = s / c;
}

extern "C" void kernel_launch(void* const* d_in, const int* in_sizes, int n_in,
                              void* d_out, int out_size, void* d_ws, size_t ws_size,
                              hipStream_t stream) {
    const float* pos    = (const float*)d_in[0];
    const int*   A      = (const int*)d_in[1];
    const int*   batch  = (const int*)d_in[2];
    const int*   esrc   = (const int*)d_in[3];
    const int*   edst   = (const int*)d_in[4];
    const float* shifts = (const float*)d_in[5];
    const float* cell   = (const float*)d_in[6];
    const float* emb    = (const float*)d_in[7];
    const float* fw1    = (const float*)d_in[8];
    const float* fb1    = (const float*)d_in[9];
    const float* fw2    = (const float*)d_in[10];
    const float* fb2    = (const float*)d_in[11];
    const float* fw3    = (const float*)d_in[12];
    const float* fb3    = (const float*)d_in[13];
    const float* fcw1   = (const float*)d_in[14];
    const float* fcw2   = (const float*)d_in[15];
    const float* fcw3   = (const float*)d_in[16];
    const float* fcw4   = (const float*)d_in[17];
    float* out = (float*)d_out;

    char* ws = (char*)d_ws;
    float* ef      = (float*)(ws + OFF_EF);
    float* T       = (float*)(ws + OFF_T);
    float* w1t     = (float*)(ws + OFF_W1T);
    float* w2t     = (float*)(ws + OFF_W2T);
    float* w3t     = (float*)(ws + OFF_W3T);
    float* ai_tab  = (float*)(ws + OFF_AI);
    int*   node_off= (int*)(ws + OFF_NOFF);
    int*   cnt_i   = (int*)(ws + OFF_NCNT);
    int*   node_cur= (int*)(ws + OFF_NCUR);
    int*   csr     = (int*)(ws + OFF_CSR);

    // cnt_i and node_cur are contiguous: one memset for both
    hipMemsetAsync(cnt_i, 0, (size_t)2 * N_NODES * 4, stream);

    ai_table_kernel<<<10, 64, 0, stream>>>(emb, fw1, fb1, fw2, fb2, fw3, fb3, ai_tab);
    mega_prep_kernel<<<MEGA_GRID, 256, 0, stream>>>(fcw1, fcw2, fcw3, fcw4, ai_tab, edst,
                                                    w1t, w2t, w3t, T, cnt_i);
    scan_kernel<<<1, 1024, 0, stream>>>(cnt_i, node_off);
    scatter_kernel<<<(N_EDGES + 255) / 256, 256, 0, stream>>>(edst, node_off, node_cur, csr);
    edge_fused_kernel<<<N_EDGES / 64, 256, 0, stream>>>(
        pos, batch, esrc, edst, shifts, cell, A, csr, w1t, w2t, w3t, T, ef);
    gather_kernel<<<(N_NODES * 36 + 255) / 256, 256, 0, stream>>>(ef, node_off, out);
}